// Round 4
// baseline (492.601 us; speedup 1.0000x reference)
//
#include <hip/hip_runtime.h>
#include <math.h>

#define B_ 8
#define C_ 128
#define N_ 16384
#define SCALE_ 0.17677669529663687f
#define EPS_ 1e-5f

#define XS_STRIDE 133   // x tile (out kernel), pixel-major [32][133]
#define WT_STRIDE 260   // w chunk (out kernel), c-major [16][260]
#define KV_STRIDE 36    // k/v tiles [128][36]
#define QS_STRIDE 132   // q / y tile [32][132]
#define AS_STRIDE 133   // attn tile [32][133]

#define XU_STRIDE 68    // packed f16-pair (uint) x tile stride: 16B aligned

#define REC_ 4224       // per-block record: 4096 P + 128 S

typedef _Float16 half8 __attribute__((ext_vector_type(8)));
typedef float floatx4 __attribute__((ext_vector_type(4)));

static __device__ inline unsigned short f16bits(float v) {
  _Float16 h = (_Float16)v;
  return __builtin_bit_cast(unsigned short, h);
}

// ---------------------------------------------------------------------------
// Kernel 1 (MFMA split-f16): k/v GEMM (rows 128..383 of w_qkv) over nchunks
// chunks of 32 px. w_kv held in registers as persistent A-fragments (hi/lo
// f16), converted once per block. x chunk staged as packed f16 hi/lo in LDS.
// D = A*B via 3 mfma_f32_16x16x32_f16 products: hihi + (hilo+lohi)*2^-11.
// exp(k) / P / S phases in fp32 as before; per-block record stores (no atomics).
// grid = B_ * bpb, block = 256 (4 waves; wave w owns kv rows [w*64, w*64+64))
// ---------------------------------------------------------------------------
__global__ __launch_bounds__(256, 2) void lin_attn_ctx(
    const float* __restrict__ x, const float* __restrict__ wqkv,
    float* __restrict__ Ws)
{
  __shared__ __align__(16) unsigned int xhiu[32 * XU_STRIDE];
  __shared__ __align__(16) unsigned int xlou[32 * XU_STRIDE];
  __shared__ __align__(16) float ks[128 * KV_STRIDE];
  __shared__ __align__(16) float vs[128 * KV_STRIDE];

  const int t = threadIdx.x;
  const int bpb = gridDim.x / B_;         // blocks per batch
  const int b = blockIdx.x / bpb;
  const int blk = blockIdx.x - b * bpb;
  const int nchunks = 512 / bpb;
  const int pbase = blk * (nchunks << 5);

  const int lane = t & 63;
  const int wave = t >> 6;                // 0..3
  const int l15 = lane & 15;
  const int quad = lane >> 4;             // 0..3

  // ---- load + convert persistent A fragments: w_kv rows [wave*64, +64) ----
  // A[m][k]: m = wave*64 + r*16 + l15, k = s*32 + quad*8 + j
  half8 ahi[4][4], alo[4][4];
#pragma unroll
  for (int r = 0; r < 4; ++r) {
#pragma unroll
    for (int s = 0; s < 4; ++s) {
      const int m = (wave << 6) + (r << 4) + l15;
      const float* wp = wqkv + (size_t)(128 + m) * C_ + (s << 5) + (quad << 3);
      float4 f0 = *(const float4*)wp;
      float4 f1 = *(const float4*)(wp + 4);
      float fv[8] = {f0.x, f0.y, f0.z, f0.w, f1.x, f1.y, f1.z, f1.w};
      half8 h, l;
#pragma unroll
      for (int j = 0; j < 8; ++j) {
        _Float16 hj = (_Float16)fv[j];
        h[j] = hj;
        l[j] = (_Float16)((fv[j] - (float)hj) * 2048.0f);
      }
      ahi[r][s] = h;
      alo[r][s] = l;
    }
  }

  float pacc[16];
#pragma unroll
  for (int u = 0; u < 16; ++u) pacc[u] = 0.f;
  float sacc = 0.f;

  for (int c4 = 0; c4 < nchunks; ++c4) {
    const int p0 = pbase + (c4 << 5);
    __syncthreads();   // prior P-phase LDS reads done; prior GEMM x-reads done
    // ---- stage x chunk: [128 ch][32 px] -> packed f16 pairs [px][kp] ----
    {
      const float* xb = x + ((size_t)b * C_) * N_ + p0;
#pragma unroll
      for (int i = 0; i < 2; ++i) {
        int lin = t + 256 * i;            // 512 items: kp = lin>>3, pxg = lin&7
        int kp = lin >> 3;                // channel pair 0..63
        int pq = (lin & 7) << 2;
        float4 f0 = *(const float4*)(xb + (size_t)(2 * kp) * N_ + pq);
        float4 f1 = *(const float4*)(xb + (size_t)(2 * kp + 1) * N_ + pq);
        float a0[4] = {f0.x, f0.y, f0.z, f0.w};
        float a1[4] = {f1.x, f1.y, f1.z, f1.w};
#pragma unroll
        for (int j = 0; j < 4; ++j) {
          _Float16 h0 = (_Float16)a0[j];
          _Float16 h1 = (_Float16)a1[j];
          float l0f = (a0[j] - (float)h0) * 2048.0f;
          float l1f = (a1[j] - (float)h1) * 2048.0f;
          unsigned int hp = ((unsigned int)f16bits(a1[j]) << 16) |
                            (unsigned int)__builtin_bit_cast(unsigned short, h0);
          (void)h1;
          unsigned int lp = ((unsigned int)f16bits(l1f) << 16) |
                            (unsigned int)f16bits(l0f);
          xhiu[(pq + j) * XU_STRIDE + kp] = hp;
          xlou[(pq + j) * XU_STRIDE + kp] = lp;
        }
      }
    }
    __syncthreads();

    // ---- MFMA GEMM: C[256 rows][32 px] ----
    floatx4 acc1[4][2], acc2[4][2];
#pragma unroll
    for (int r = 0; r < 4; ++r)
#pragma unroll
      for (int c = 0; c < 2; ++c) {
        acc1[r][c] = (floatx4){0.f, 0.f, 0.f, 0.f};
        acc2[r][c] = (floatx4){0.f, 0.f, 0.f, 0.f};
      }
#pragma unroll
    for (int s = 0; s < 4; ++s) {
#pragma unroll
      for (int c = 0; c < 2; ++c) {
        int n = (c << 4) + l15;
        int off = n * XU_STRIDE + (s << 4) + (quad << 2);
        uint4 uh = *(const uint4*)&xhiu[off];
        uint4 ul = *(const uint4*)&xlou[off];
        half8 bh = __builtin_bit_cast(half8, uh);
        half8 bl = __builtin_bit_cast(half8, ul);
#pragma unroll
        for (int r = 0; r < 4; ++r) {
          acc1[r][c] = __builtin_amdgcn_mfma_f32_16x16x32_f16(ahi[r][s], bh, acc1[r][c], 0, 0, 0);
          acc2[r][c] = __builtin_amdgcn_mfma_f32_16x16x32_f16(ahi[r][s], bl, acc2[r][c], 0, 0, 0);
          acc2[r][c] = __builtin_amdgcn_mfma_f32_16x16x32_f16(alo[r][s], bh, acc2[r][c], 0, 0, 0);
        }
      }
    }
    // ---- write C -> ks (exp) / vs (raw); waves 0,1 = k rows, 2,3 = v ----
#pragma unroll
    for (int r = 0; r < 4; ++r) {
#pragma unroll
      for (int c = 0; c < 2; ++c) {
        int px = (c << 4) + l15;
#pragma unroll
        for (int reg = 0; reg < 4; ++reg) {
          float val = acc1[r][c][reg] + acc2[r][c][reg] * (1.0f / 2048.0f);
          int row = (wave << 6) + (r << 4) + (quad << 2) + reg;
          if (row < 128) ks[row * KV_STRIDE + px] = __expf(val) ;
          else           vs[(row - 128) * KV_STRIDE + px] = val;
        }
      }
    }
    __syncthreads();
    // ---- S partial ----
    {
      int r = t >> 1, half = t & 1;
#pragma unroll
      for (int p = 0; p < 16; ++p) sacc += ks[r * KV_STRIDE + half * 16 + p];
    }
    // ---- P partial: thread -> (h = t>>6, dk = (t>>1)&31, dv half = t&1) ----
    {
      int h = t >> 6, dk = (t >> 1) & 31, dvh = t & 1;
      float ek[32];
      const float* krow = &ks[(h * 32 + dk) * KV_STRIDE];
#pragma unroll
      for (int q = 0; q < 8; ++q) {
        float4 f = *(const float4*)&krow[q * 4];
        ek[q * 4 + 0] = f.x; ek[q * 4 + 1] = f.y;
        ek[q * 4 + 2] = f.z; ek[q * 4 + 3] = f.w;
      }
#pragma unroll
      for (int u = 0; u < 16; ++u) {
        int dv = dvh * 16 + u;
        const float* vrow = &vs[(h * 32 + dv) * KV_STRIDE];
        float p = 0.f;
#pragma unroll
        for (int q = 0; q < 8; ++q) {
          float4 f = *(const float4*)&vrow[q * 4];
          p += ek[q * 4 + 0] * f.x + ek[q * 4 + 1] * f.y +
               ek[q * 4 + 2] * f.z + ek[q * 4 + 3] * f.w;
        }
        pacc[u] += p;
      }
    }
  }

  // plain coalesced stores into private record (no atomics)
  {
    float* rec = Ws + (size_t)blockIdx.x * REC_;
    int h = t >> 6, dk = (t >> 1) & 31, dvh = t & 1;
    float* dst = &rec[(h * 32 + dk) * 32 + dvh * 16];
#pragma unroll
    for (int q = 0; q < 4; ++q) {
      float4 f;
      f.x = pacc[q * 4 + 0]; f.y = pacc[q * 4 + 1];
      f.z = pacc[q * 4 + 2]; f.w = pacc[q * 4 + 3];
      *(float4*)&dst[q * 4] = f;
    }
    int r = t >> 1, half = t & 1;
    float s = sacc + __shfl_xor(sacc, 1);
    if (half == 0) rec[4096 + r] = s;
  }
}

// ---------------------------------------------------------------------------
// Reduction: sum `slots` records per batch -> final P[b][4096], S[b][128]
// grid = 132, block = 256  (8 * 4224 = 33792 outputs)
// ---------------------------------------------------------------------------
__global__ void lin_attn_reduce(const float* __restrict__ Ws, int slots,
                                float* __restrict__ Pf, float* __restrict__ Sf)
{
  int idx = blockIdx.x * 256 + threadIdx.x;
  int b = idx / REC_;
  int j = idx - b * REC_;
  const float* src = Ws + (size_t)b * slots * REC_ + j;
  float s0 = 0.f, s1 = 0.f, s2 = 0.f, s3 = 0.f;
  for (int k = 0; k < slots; k += 4) {
    s0 += src[(size_t)(k + 0) * REC_];
    s1 += src[(size_t)(k + 1) * REC_];
    s2 += src[(size_t)(k + 2) * REC_];
    s3 += src[(size_t)(k + 3) * REC_];
  }
  float s = (s0 + s1) + (s2 + s3);
  if (j < 4096) Pf[b * 4096 + j] = s;
  else          Sf[b * 128 + (j - 4096)] = s;
}

// ---------------------------------------------------------------------------
// Kernel 2 (UNCHANGED): q GEMM -> per-pixel head softmax*scale ->
// attn = ctx^T q -> W_out GEMM + bias -> channel LayerNorm -> out.
// grid = B_ * 512, block = 256
// ---------------------------------------------------------------------------
__global__ __launch_bounds__(256, 2) void lin_attn_out(
    const float* __restrict__ x, const float* __restrict__ wqkv,
    const float* __restrict__ wout, const float* __restrict__ bout,
    const float* __restrict__ alpha, const float* __restrict__ beta,
    const float* __restrict__ Sg, const float* __restrict__ Pg,
    float* __restrict__ out)
{
  __shared__ __align__(16) float xs[32 * XS_STRIDE];  // x tile, later ctx[4][32][32]
  __shared__ __align__(16) float wt[16 * WT_STRIDE];
  __shared__ __align__(16) float qs[32 * QS_STRIDE];  // q tile, later y tile
  __shared__ __align__(16) float as_[32 * AS_STRIDE]; // attn tile
  __shared__ float red_s[256];
  __shared__ float red_q[256];

  const int t = threadIdx.x;
  const int b = blockIdx.x >> 9;
  const int p0 = (blockIdx.x & 511) << 5;

  // stage x tile
  {
    const float* xb = x + ((size_t)b * C_) * N_ + p0;
#pragma unroll
    for (int i = 0; i < 4; ++i) {
      int lin = t + 256 * i;
      int c = lin >> 3;
      int pq = (lin & 7) << 2;
      float4 f = *(const float4*)(xb + (size_t)c * N_ + pq);
      xs[(pq + 0) * XS_STRIDE + c] = f.x;
      xs[(pq + 1) * XS_STRIDE + c] = f.y;
      xs[(pq + 2) * XS_STRIDE + c] = f.z;
      xs[(pq + 3) * XS_STRIDE + c] = f.w;
    }
  }

  const int pg = t & 7;   // px = pg*4..pg*4+3
  const int rg = t >> 3;  // rows rg*4..rg*4+3 (128 rows)

  float acc[4][4];
#pragma unroll
  for (int i = 0; i < 4; ++i)
#pragma unroll
    for (int j = 0; j < 4; ++j) acc[i][j] = 0.f;

  // ---- q GEMM ----
  for (int kc = 0; kc < 8; ++kc) {
    __syncthreads();
#pragma unroll
    for (int i = 0; i < 2; ++i) {
      int lin = t + 256 * i;            // 512 float4s
      int r = lin >> 2;                 // 0..127
      int cq = (lin & 3) << 2;
      float4 f = *(const float4*)(wqkv + (size_t)r * C_ + (kc << 4) + cq);
      wt[(cq + 0) * WT_STRIDE + r] = f.x;
      wt[(cq + 1) * WT_STRIDE + r] = f.y;
      wt[(cq + 2) * WT_STRIDE + r] = f.z;
      wt[(cq + 3) * WT_STRIDE + r] = f.w;
    }
    __syncthreads();
#pragma unroll
    for (int c = 0; c < 16; ++c) {
      float4 wv = *(const float4*)&wt[c * WT_STRIDE + rg * 4];
      int col = (kc << 4) + c;
#pragma unroll
      for (int j = 0; j < 4; ++j) {
        float xv = xs[(pg * 4 + j) * XS_STRIDE + col];
        acc[0][j] += wv.x * xv; acc[1][j] += wv.y * xv;
        acc[2][j] += wv.z * xv; acc[3][j] += wv.w * xv;
      }
    }
  }
  // write q tile (pixel-major)
#pragma unroll
  for (int i = 0; i < 4; ++i)
#pragma unroll
    for (int j = 0; j < 4; ++j)
      qs[(pg * 4 + j) * QS_STRIDE + rg * 4 + i] = acc[i][j];
  __syncthreads();
  // stage normalized context into xs region: ctx = P / (S * n)
#pragma unroll
  for (int i = 0; i < 16; ++i) {
    int lin = t + 256 * i;              // 4096 entries: h*1024 + dk*32 + dv
    xs[lin] = Pg[b * 4096 + lin] / (Sg[b * 128 + (lin >> 5)] * 16384.f);
  }
  __syncthreads();
  // ---- per-pixel head softmax + attn matvec ----
  {
    int px = t & 31, h = (t >> 5) & 3, dvh = t >> 7;
    float qv[32];
#pragma unroll
    for (int q = 0; q < 8; ++q) {
      float4 f = *(const float4*)&qs[px * QS_STRIDE + h * 32 + q * 4];
      qv[q * 4 + 0] = f.x; qv[q * 4 + 1] = f.y;
      qv[q * 4 + 2] = f.z; qv[q * 4 + 3] = f.w;
    }
    float m = qv[0];
#pragma unroll
    for (int j = 1; j < 32; ++j) m = fmaxf(m, qv[j]);
    float s = 0.f;
#pragma unroll
    for (int j = 0; j < 32; ++j) { qv[j] = expf(qv[j] - m); s += qv[j]; }
    float inv = SCALE_ / s;
#pragma unroll
    for (int j = 0; j < 32; ++j) qv[j] *= inv;
    float av[16];
#pragma unroll
    for (int u = 0; u < 16; ++u) av[u] = 0.f;
#pragma unroll
    for (int dk = 0; dk < 32; ++dk) {
      float qk = qv[dk];
      const float* crow = &xs[h * 1024 + dk * 32 + dvh * 16];
#pragma unroll
      for (int u = 0; u < 4; ++u) {
        float4 f = *(const float4*)&crow[u * 4];
        av[u * 4 + 0] += qk * f.x; av[u * 4 + 1] += qk * f.y;
        av[u * 4 + 2] += qk * f.z; av[u * 4 + 3] += qk * f.w;
      }
    }
#pragma unroll
    for (int u = 0; u < 16; ++u)
      as_[px * AS_STRIDE + h * 32 + dvh * 16 + u] = av[u];
  }
  // ---- W_out GEMM ----
#pragma unroll
  for (int i = 0; i < 4; ++i)
#pragma unroll
    for (int j = 0; j < 4; ++j) acc[i][j] = 0.f;
  for (int kc = 0; kc < 8; ++kc) {
    __syncthreads();
#pragma unroll
    for (int i = 0; i < 2; ++i) {
      int lin = t + 256 * i;
      int r = lin >> 2;
      int cq = (lin & 3) << 2;
      float4 f = *(const float4*)(wout + (size_t)r * C_ + (kc << 4) + cq);
      wt[(cq + 0) * WT_STRIDE + r] = f.x;
      wt[(cq + 1) * WT_STRIDE + r] = f.y;
      wt[(cq + 2) * WT_STRIDE + r] = f.z;
      wt[(cq + 3) * WT_STRIDE + r] = f.w;
    }
    __syncthreads();
#pragma unroll
    for (int c = 0; c < 16; ++c) {
      float4 wv = *(const float4*)&wt[c * WT_STRIDE + rg * 4];
      int col = (kc << 4) + c;
#pragma unroll
      for (int j = 0; j < 4; ++j) {
        float xv = as_[(pg * 4 + j) * AS_STRIDE + col];
        acc[0][j] += wv.x * xv; acc[1][j] += wv.y * xv;
        acc[2][j] += wv.z * xv; acc[3][j] += wv.w * xv;
      }
    }
  }
  // bias + write y tile into qs region (q tile is dead)
  {
    float bias[4];
#pragma unroll
    for (int i = 0; i < 4; ++i) bias[i] = bout[rg * 4 + i];
#pragma unroll
    for (int i = 0; i < 4; ++i)
#pragma unroll
      for (int j = 0; j < 4; ++j)
        qs[(pg * 4 + j) * QS_STRIDE + rg * 4 + i] = acc[i][j] + bias[i];
  }
  __syncthreads();
  // ---- LayerNorm over 128 channels per pixel ----
  {
    int px = t & 31, cg = t >> 5;       // cg: 8 groups of 16 channels
    float y[16];
#pragma unroll
    for (int u = 0; u < 4; ++u) {
      float4 f = *(const float4*)&qs[px * QS_STRIDE + cg * 16 + u * 4];
      y[u * 4 + 0] = f.x; y[u * 4 + 1] = f.y;
      y[u * 4 + 2] = f.z; y[u * 4 + 3] = f.w;
    }
    float sm = 0.f, sq = 0.f;
#pragma unroll
    for (int u = 0; u < 16; ++u) { sm += y[u]; sq += y[u] * y[u]; }
    red_s[cg * 32 + px] = sm;
    red_q[cg * 32 + px] = sq;
    __syncthreads();
    float ts = 0.f, tq = 0.f;
#pragma unroll
    for (int g = 0; g < 8; ++g) { ts += red_s[g * 32 + px]; tq += red_q[g * 32 + px]; }
    float mean = ts * (1.f / 128.f);
    float var = tq * (1.f / 128.f) - mean * mean;
    float rstd = 1.f / sqrtf(var + EPS_);
    float* ob = out + ((size_t)b * C_) * N_ + p0 + px;
#pragma unroll
    for (int u = 0; u < 16; ++u) {
      int ch = cg * 16 + u;
      ob[(size_t)ch * N_] = (y[u] - mean) * rstd * alpha[ch] + beta[ch];
    }
  }
}

extern "C" void kernel_launch(void* const* d_in, const int* in_sizes, int n_in,
                              void* d_out, int out_size, void* d_ws, size_t ws_size,
                              hipStream_t stream) {
  const float* x     = (const float*)d_in[0];
  const float* wqkv  = (const float*)d_in[1];
  const float* wout  = (const float*)d_in[2];
  const float* bout  = (const float*)d_in[3];
  const float* alpha = (const float*)d_in[4];
  const float* beta  = (const float*)d_in[5];
  float* outp = (float*)d_out;

  // pick slots/batch by workspace size (deterministic -> graph-safe)
  size_t need128 = ((size_t)B_ * 128 * REC_ + B_ * 4096 + B_ * 128) * sizeof(float);
  int bpb = (ws_size >= need128) ? 128 : 32;

  float* Ws = (float*)d_ws;                          // [B*bpb][4224] records
  float* Pf = Ws + (size_t)B_ * bpb * REC_;          // [B][4096]
  float* Sf = Pf + (size_t)B_ * 4096;                // [B][128]

  lin_attn_ctx<<<dim3(B_ * bpb), dim3(256), 0, stream>>>(x, wqkv, Ws);
  lin_attn_reduce<<<dim3(132), dim3(256), 0, stream>>>(Ws, bpb, Pf, Sf);
  lin_attn_out<<<dim3(B_ * 512), dim3(256), 0, stream>>>(x, wqkv, wout, bout,
                                                         alpha, beta, Sf, Pf, outp);
}

// Round 5
// 438.320 us; speedup vs baseline: 1.1238x; 1.1238x over previous
//
#include <hip/hip_runtime.h>
#include <math.h>

#define B_ 8
#define C_ 128
#define N_ 16384
#define SCALE_ 0.17677669529663687f
#define EPS_ 1e-5f

#define KV_STRIDE 36    // k/v tiles [128][36] (ctx kernel)
#define XU_STRIDE 68    // packed f16-pair (uint) tile stride
#define QS_STRIDE 132   // q / y pixel-major tile [32][132] (out kernel)

#define REC_ 4224       // per-block record: 4096 P + 128 S

typedef _Float16 half8 __attribute__((ext_vector_type(8)));
typedef float floatx4 __attribute__((ext_vector_type(4)));

static __device__ inline unsigned short f16bits(float v) {
  _Float16 h = (_Float16)v;
  return __builtin_bit_cast(unsigned short, h);
}

static __device__ inline void split8(const float* p, half8& hi, half8& lo) {
  float4 f0 = *(const float4*)p;
  float4 f1 = *(const float4*)(p + 4);
  float fv[8] = {f0.x, f0.y, f0.z, f0.w, f1.x, f1.y, f1.z, f1.w};
#pragma unroll
  for (int j = 0; j < 8; ++j) {
    _Float16 hj = (_Float16)fv[j];
    hi[j] = hj;
    lo[j] = (_Float16)((fv[j] - (float)hj) * 2048.0f);
  }
}

// ---------------------------------------------------------------------------
// Kernel 1 (UNCHANGED from R3): k/v GEMM via split-f16 MFMA, exp(k), fp32
// P/S partial phase, per-block record stores.
// grid = B_ * bpb, block = 256
// ---------------------------------------------------------------------------
__global__ __launch_bounds__(256, 2) void lin_attn_ctx(
    const float* __restrict__ x, const float* __restrict__ wqkv,
    float* __restrict__ Ws)
{
  __shared__ __align__(16) unsigned int xhiu[32 * XU_STRIDE];
  __shared__ __align__(16) unsigned int xlou[32 * XU_STRIDE];
  __shared__ __align__(16) float ks[128 * KV_STRIDE];
  __shared__ __align__(16) float vs[128 * KV_STRIDE];

  const int t = threadIdx.x;
  const int bpb = gridDim.x / B_;
  const int b = blockIdx.x / bpb;
  const int blk = blockIdx.x - b * bpb;
  const int nchunks = 512 / bpb;
  const int pbase = blk * (nchunks << 5);

  const int lane = t & 63;
  const int wave = t >> 6;
  const int l15 = lane & 15;
  const int quad = lane >> 4;

  half8 ahi[4][4], alo[4][4];
#pragma unroll
  for (int r = 0; r < 4; ++r) {
#pragma unroll
    for (int s = 0; s < 4; ++s) {
      const int m = (wave << 6) + (r << 4) + l15;
      split8(wqkv + (size_t)(128 + m) * C_ + (s << 5) + (quad << 3),
             ahi[r][s], alo[r][s]);
    }
  }

  float pacc[16];
#pragma unroll
  for (int u = 0; u < 16; ++u) pacc[u] = 0.f;
  float sacc = 0.f;

  for (int c4 = 0; c4 < nchunks; ++c4) {
    const int p0 = pbase + (c4 << 5);
    __syncthreads();
    {
      const float* xb = x + ((size_t)b * C_) * N_ + p0;
#pragma unroll
      for (int i = 0; i < 2; ++i) {
        int lin = t + 256 * i;
        int kp = lin >> 3;
        int pq = (lin & 7) << 2;
        float4 f0 = *(const float4*)(xb + (size_t)(2 * kp) * N_ + pq);
        float4 f1 = *(const float4*)(xb + (size_t)(2 * kp + 1) * N_ + pq);
        float a0[4] = {f0.x, f0.y, f0.z, f0.w};
        float a1[4] = {f1.x, f1.y, f1.z, f1.w};
#pragma unroll
        for (int j = 0; j < 4; ++j) {
          _Float16 h0 = (_Float16)a0[j];
          float l0f = (a0[j] - (float)h0) * 2048.0f;
          float l1f = (a1[j] - (float)((_Float16)a1[j])) * 2048.0f;
          unsigned int hp = ((unsigned int)f16bits(a1[j]) << 16) |
                            (unsigned int)__builtin_bit_cast(unsigned short, h0);
          unsigned int lp = ((unsigned int)f16bits(l1f) << 16) |
                            (unsigned int)f16bits(l0f);
          xhiu[(pq + j) * XU_STRIDE + kp] = hp;
          xlou[(pq + j) * XU_STRIDE + kp] = lp;
        }
      }
    }
    __syncthreads();

    floatx4 acc1[4][2], acc2[4][2];
#pragma unroll
    for (int r = 0; r < 4; ++r)
#pragma unroll
      for (int c = 0; c < 2; ++c) {
        acc1[r][c] = (floatx4){0.f, 0.f, 0.f, 0.f};
        acc2[r][c] = (floatx4){0.f, 0.f, 0.f, 0.f};
      }
#pragma unroll
    for (int s = 0; s < 4; ++s) {
#pragma unroll
      for (int c = 0; c < 2; ++c) {
        int n = (c << 4) + l15;
        int off = n * XU_STRIDE + (s << 4) + (quad << 2);
        uint4 uh = *(const uint4*)&xhiu[off];
        uint4 ul = *(const uint4*)&xlou[off];
        half8 bh = __builtin_bit_cast(half8, uh);
        half8 bl = __builtin_bit_cast(half8, ul);
#pragma unroll
        for (int r = 0; r < 4; ++r) {
          acc1[r][c] = __builtin_amdgcn_mfma_f32_16x16x32_f16(ahi[r][s], bh, acc1[r][c], 0, 0, 0);
          acc2[r][c] = __builtin_amdgcn_mfma_f32_16x16x32_f16(ahi[r][s], bl, acc2[r][c], 0, 0, 0);
          acc2[r][c] = __builtin_amdgcn_mfma_f32_16x16x32_f16(alo[r][s], bh, acc2[r][c], 0, 0, 0);
        }
      }
    }
#pragma unroll
    for (int r = 0; r < 4; ++r) {
#pragma unroll
      for (int c = 0; c < 2; ++c) {
        int px = (c << 4) + l15;
#pragma unroll
        for (int reg = 0; reg < 4; ++reg) {
          float val = acc1[r][c][reg] + acc2[r][c][reg] * (1.0f / 2048.0f);
          int row = (wave << 6) + (r << 4) + (quad << 2) + reg;
          if (row < 128) ks[row * KV_STRIDE + px] = __expf(val);
          else           vs[(row - 128) * KV_STRIDE + px] = val;
        }
      }
    }
    __syncthreads();
    {
      int r = t >> 1, half = t & 1;
#pragma unroll
      for (int p = 0; p < 16; ++p) sacc += ks[r * KV_STRIDE + half * 16 + p];
    }
    {
      int h = t >> 6, dk = (t >> 1) & 31, dvh = t & 1;
      float ek[32];
      const float* krow = &ks[(h * 32 + dk) * KV_STRIDE];
#pragma unroll
      for (int q = 0; q < 8; ++q) {
        float4 f = *(const float4*)&krow[q * 4];
        ek[q * 4 + 0] = f.x; ek[q * 4 + 1] = f.y;
        ek[q * 4 + 2] = f.z; ek[q * 4 + 3] = f.w;
      }
#pragma unroll
      for (int u = 0; u < 16; ++u) {
        int dv = dvh * 16 + u;
        const float* vrow = &vs[(h * 32 + dv) * KV_STRIDE];
        float p = 0.f;
#pragma unroll
        for (int q = 0; q < 8; ++q) {
          float4 f = *(const float4*)&vrow[q * 4];
          p += ek[q * 4 + 0] * f.x + ek[q * 4 + 1] * f.y +
               ek[q * 4 + 2] * f.z + ek[q * 4 + 3] * f.w;
        }
        pacc[u] += p;
      }
    }
  }

  {
    float* rec = Ws + (size_t)blockIdx.x * REC_;
    int h = t >> 6, dk = (t >> 1) & 31, dvh = t & 1;
    float* dst = &rec[(h * 32 + dk) * 32 + dvh * 16];
#pragma unroll
    for (int q = 0; q < 4; ++q) {
      float4 f;
      f.x = pacc[q * 4 + 0]; f.y = pacc[q * 4 + 1];
      f.z = pacc[q * 4 + 2]; f.w = pacc[q * 4 + 3];
      *(float4*)&dst[q * 4] = f;
    }
    int r = t >> 1, half = t & 1;
    float s = sacc + __shfl_xor(sacc, 1);
    if (half == 0) rec[4096 + r] = s;
  }
}

// ---------------------------------------------------------------------------
// Reduction: sum `slots` records per batch -> final P[b][4096], S[b][128]
// grid = 132, block = 256
// ---------------------------------------------------------------------------
__global__ void lin_attn_reduce(const float* __restrict__ Ws, int slots,
                                float* __restrict__ Pf, float* __restrict__ Sf)
{
  int idx = blockIdx.x * 256 + threadIdx.x;
  int b = idx / REC_;
  int j = idx - b * REC_;
  const float* src = Ws + (size_t)b * slots * REC_ + j;
  float s0 = 0.f, s1 = 0.f, s2 = 0.f, s3 = 0.f;
  for (int k = 0; k < slots; k += 4) {
    s0 += src[(size_t)(k + 0) * REC_];
    s1 += src[(size_t)(k + 1) * REC_];
    s2 += src[(size_t)(k + 2) * REC_];
    s3 += src[(size_t)(k + 3) * REC_];
  }
  float s = (s0 + s1) + (s2 + s3);
  if (j < 4096) Pf[b * 4096 + j] = s;
  else          Sf[b * 128 + (j - 4096)] = s;
}

// ---------------------------------------------------------------------------
// NEW: G[b][o][h*32+dk] = SCALE * sum_dv wout[o][h*32+dv] * ctx_h[dk][dv],
// ctx_h[dk][dv] = P[h][dk][dv] / (S[h*32+dk] * N).  grid = B_*64, block = 256
// ---------------------------------------------------------------------------
__global__ void lin_attn_gmat(const float* __restrict__ Pf,
                              const float* __restrict__ Sf,
                              const float* __restrict__ wout,
                              float* __restrict__ G)
{
  __shared__ float ctxs[4096];
  const int t = threadIdx.x;
  const int b = blockIdx.x >> 6;
  const int o0 = (blockIdx.x & 63) << 1;
#pragma unroll
  for (int i = 0; i < 16; ++i) {
    int lin = t + 256 * i;
    ctxs[lin] = Pf[b * 4096 + lin] / (Sf[b * 128 + (lin >> 5)] * 16384.f);
  }
  __syncthreads();
  const int o = o0 + (t >> 7);
  const int col = t & 127;
  const int h = col >> 5, dk = col & 31;
  const float* wrow = wout + (size_t)o * 128 + h * 32;
  const float* crow = &ctxs[h * 1024 + dk * 32];
  float s = 0.f;
#pragma unroll
  for (int q = 0; q < 8; ++q) {
    float4 w4 = *(const float4*)&wrow[q * 4];
    float4 c4 = *(const float4*)&crow[q * 4];
    s += w4.x * c4.x + w4.y * c4.y + w4.z * c4.z + w4.w * c4.w;
  }
  G[(size_t)b * 16384 + (size_t)o * 128 + col] = s * SCALE_;
}

// ---------------------------------------------------------------------------
// Kernel 2 (REWRITTEN): per 32-px chunk: split-f16 MFMA q = w_q*x ->
// per-pixel head softmax -> split-f16 MFMA y = G*qhat -> bias + LayerNorm.
// Persistent w_q and G fragments in registers. grid = B_*128, block = 256
// ---------------------------------------------------------------------------
__global__ __launch_bounds__(256, 2) void lin_attn_out(
    const float* __restrict__ x, const float* __restrict__ wqkv,
    const float* __restrict__ G, const float* __restrict__ bout,
    const float* __restrict__ alpha, const float* __restrict__ beta,
    float* __restrict__ out)
{
  __shared__ __align__(16) unsigned int bufA[2 * 32 * XU_STRIDE]; // x | qhat (hi,lo)
  __shared__ __align__(16) float bufB[32 * QS_STRIDE];            // q | y pixel-major
  __shared__ float red_s[256];
  __shared__ float red_q[256];

  unsigned int* xhiu = bufA;
  unsigned int* xlou = bufA + 32 * XU_STRIDE;

  const int t = threadIdx.x;
  const int bpb = gridDim.x / B_;         // 128
  const int b = blockIdx.x / bpb;
  const int blk = blockIdx.x - b * bpb;
  const int nchunks = 512 / bpb;          // 4
  const int pbase = blk * (nchunks << 5);

  const int lane = t & 63;
  const int wave = t >> 6;                // 0..3 -> channel rows [wave*32, +32)
  const int l15 = lane & 15;
  const int quad = lane >> 4;

  // persistent A fragments: w_q rows and G rows [wave*32, +32)
  half8 qhiA[2][4], qloA[2][4], ghiA[2][4], gloA[2][4];
#pragma unroll
  for (int r = 0; r < 2; ++r) {
#pragma unroll
    for (int s = 0; s < 4; ++s) {
      const int m = (wave << 5) + (r << 4) + l15;
      split8(wqkv + (size_t)m * C_ + (s << 5) + (quad << 3), qhiA[r][s], qloA[r][s]);
      split8(G + (size_t)b * 16384 + (size_t)m * 128 + (s << 5) + (quad << 3),
             ghiA[r][s], gloA[r][s]);
    }
  }

  for (int c4 = 0; c4 < nchunks; ++c4) {
    const int p0 = pbase + (c4 << 5);
    __syncthreads();   // prior chunk's bufA (qhat) reads done
    // ---- stage x chunk as packed f16 hi/lo pairs ----
    {
      const float* xb = x + ((size_t)b * C_) * N_ + p0;
#pragma unroll
      for (int i = 0; i < 2; ++i) {
        int lin = t + 256 * i;
        int kp = lin >> 3;
        int pq = (lin & 7) << 2;
        float4 f0 = *(const float4*)(xb + (size_t)(2 * kp) * N_ + pq);
        float4 f1 = *(const float4*)(xb + (size_t)(2 * kp + 1) * N_ + pq);
        float a0[4] = {f0.x, f0.y, f0.z, f0.w};
        float a1[4] = {f1.x, f1.y, f1.z, f1.w};
#pragma unroll
        for (int j = 0; j < 4; ++j) {
          _Float16 h0 = (_Float16)a0[j];
          float l0f = (a0[j] - (float)h0) * 2048.0f;
          float l1f = (a1[j] - (float)((_Float16)a1[j])) * 2048.0f;
          unsigned int hp = ((unsigned int)f16bits(a1[j]) << 16) |
                            (unsigned int)__builtin_bit_cast(unsigned short, h0);
          unsigned int lp = ((unsigned int)f16bits(l1f) << 16) |
                            (unsigned int)f16bits(l0f);
          xhiu[(pq + j) * XU_STRIDE + kp] = hp;
          xlou[(pq + j) * XU_STRIDE + kp] = lp;
        }
      }
    }
    __syncthreads();

    // ---- q GEMM: q[wave rows][32 px] ----
    {
      floatx4 a1[2][2], a2[2][2];
#pragma unroll
      for (int r = 0; r < 2; ++r)
#pragma unroll
        for (int c = 0; c < 2; ++c) {
          a1[r][c] = (floatx4){0.f, 0.f, 0.f, 0.f};
          a2[r][c] = (floatx4){0.f, 0.f, 0.f, 0.f};
        }
#pragma unroll
      for (int s = 0; s < 4; ++s) {
#pragma unroll
        for (int c = 0; c < 2; ++c) {
          int off = ((c << 4) + l15) * XU_STRIDE + (s << 4) + (quad << 2);
          half8 bh = __builtin_bit_cast(half8, *(const uint4*)&xhiu[off]);
          half8 bl = __builtin_bit_cast(half8, *(const uint4*)&xlou[off]);
#pragma unroll
          for (int r = 0; r < 2; ++r) {
            a1[r][c] = __builtin_amdgcn_mfma_f32_16x16x32_f16(qhiA[r][s], bh, a1[r][c], 0, 0, 0);
            a2[r][c] = __builtin_amdgcn_mfma_f32_16x16x32_f16(qhiA[r][s], bl, a2[r][c], 0, 0, 0);
            a2[r][c] = __builtin_amdgcn_mfma_f32_16x16x32_f16(qloA[r][s], bh, a2[r][c], 0, 0, 0);
          }
        }
      }
      // q -> bufB pixel-major (float4 per (r,c): 4 consecutive channels)
#pragma unroll
      for (int r = 0; r < 2; ++r)
#pragma unroll
        for (int c = 0; c < 2; ++c) {
          float4 f;
          f.x = a1[r][c][0] + a2[r][c][0] * (1.0f / 2048.0f);
          f.y = a1[r][c][1] + a2[r][c][1] * (1.0f / 2048.0f);
          f.z = a1[r][c][2] + a2[r][c][2] * (1.0f / 2048.0f);
          f.w = a1[r][c][3] + a2[r][c][3] * (1.0f / 2048.0f);
          int px = (c << 4) + l15;
          int ch = (wave << 5) + (r << 4) + (quad << 2);
          *(float4*)&bufB[px * QS_STRIDE + ch] = f;
        }
    }
    __syncthreads();

    // ---- per-pixel head softmax; write qhat packed hi/lo over bufA ----
    {
      int px = t & 31, h = (t >> 5) & 3, dvh = t >> 7;
      float qv[32];
#pragma unroll
      for (int q = 0; q < 8; ++q) {
        float4 f = *(const float4*)&bufB[px * QS_STRIDE + h * 32 + q * 4];
        qv[q * 4 + 0] = f.x; qv[q * 4 + 1] = f.y;
        qv[q * 4 + 2] = f.z; qv[q * 4 + 3] = f.w;
      }
      float m = qv[0];
#pragma unroll
      for (int j = 1; j < 32; ++j) m = fmaxf(m, qv[j]);
      float s = 0.f;
#pragma unroll
      for (int j = 0; j < 32; ++j) { qv[j] = __expf(qv[j] - m); s += qv[j]; }
      float inv = 1.0f / s;   // scale folded into G
#pragma unroll
      for (int w2 = 0; w2 < 8; ++w2) {
        int j = dvh * 16 + 2 * w2;
        float v0 = qv[j] * inv, v1 = qv[j + 1] * inv;
        _Float16 h0 = (_Float16)v0;
        _Float16 h1 = (_Float16)v1;
        float l0f = (v0 - (float)h0) * 2048.0f;
        float l1f = (v1 - (float)h1) * 2048.0f;
        unsigned int hp = ((unsigned int)__builtin_bit_cast(unsigned short, h1) << 16) |
                          (unsigned int)__builtin_bit_cast(unsigned short, h0);
        unsigned int lp = ((unsigned int)f16bits(l1f) << 16) |
                          (unsigned int)f16bits(l0f);
        int kp = h * 16 + dvh * 8 + w2;
        xhiu[px * XU_STRIDE + kp] = hp;
        xlou[px * XU_STRIDE + kp] = lp;
      }
    }
    __syncthreads();

    // ---- y GEMM: y = G * qhat ----
    {
      floatx4 a1[2][2], a2[2][2];
#pragma unroll
      for (int r = 0; r < 2; ++r)
#pragma unroll
        for (int c = 0; c < 2; ++c) {
          a1[r][c] = (floatx4){0.f, 0.f, 0.f, 0.f};
          a2[r][c] = (floatx4){0.f, 0.f, 0.f, 0.f};
        }
#pragma unroll
      for (int s = 0; s < 4; ++s) {
#pragma unroll
        for (int c = 0; c < 2; ++c) {
          int off = ((c << 4) + l15) * XU_STRIDE + (s << 4) + (quad << 2);
          half8 bh = __builtin_bit_cast(half8, *(const uint4*)&xhiu[off]);
          half8 bl = __builtin_bit_cast(half8, *(const uint4*)&xlou[off]);
#pragma unroll
          for (int r = 0; r < 2; ++r) {
            a1[r][c] = __builtin_amdgcn_mfma_f32_16x16x32_f16(ghiA[r][s], bh, a1[r][c], 0, 0, 0);
            a2[r][c] = __builtin_amdgcn_mfma_f32_16x16x32_f16(ghiA[r][s], bl, a2[r][c], 0, 0, 0);
            a2[r][c] = __builtin_amdgcn_mfma_f32_16x16x32_f16(gloA[r][s], bh, a2[r][c], 0, 0, 0);
          }
        }
      }
#pragma unroll
      for (int r = 0; r < 2; ++r)
#pragma unroll
        for (int c = 0; c < 2; ++c) {
          float4 f;
          f.x = a1[r][c][0] + a2[r][c][0] * (1.0f / 2048.0f);
          f.y = a1[r][c][1] + a2[r][c][1] * (1.0f / 2048.0f);
          f.z = a1[r][c][2] + a2[r][c][2] * (1.0f / 2048.0f);
          f.w = a1[r][c][3] + a2[r][c][3] * (1.0f / 2048.0f);
          int px = (c << 4) + l15;
          int ch = (wave << 5) + (r << 4) + (quad << 2);
          *(float4*)&bufB[px * QS_STRIDE + ch] = f;
        }
    }
    __syncthreads();

    // ---- bias + LayerNorm over 128 channels per pixel ----
    {
      int px = t & 31, cg = t >> 5;
      float y[16];
#pragma unroll
      for (int u = 0; u < 4; ++u) {
        float4 f = *(const float4*)&bufB[px * QS_STRIDE + cg * 16 + u * 4];
        y[u * 4 + 0] = f.x + bout[cg * 16 + u * 4 + 0];
        y[u * 4 + 1] = f.y + bout[cg * 16 + u * 4 + 1];
        y[u * 4 + 2] = f.z + bout[cg * 16 + u * 4 + 2];
        y[u * 4 + 3] = f.w + bout[cg * 16 + u * 4 + 3];
      }
      float sm = 0.f, sq = 0.f;
#pragma unroll
      for (int u = 0; u < 16; ++u) { sm += y[u]; sq += y[u] * y[u]; }
      red_s[cg * 32 + px] = sm;
      red_q[cg * 32 + px] = sq;
      __syncthreads();
      float ts = 0.f, tq = 0.f;
#pragma unroll
      for (int g = 0; g < 8; ++g) { ts += red_s[g * 32 + px]; tq += red_q[g * 32 + px]; }
      float mean = ts * (1.f / 128.f);
      float var = tq * (1.f / 128.f) - mean * mean;
      float rstd = 1.f / sqrtf(var + EPS_);
      float* ob = out + ((size_t)b * C_) * N_ + p0 + px;
#pragma unroll
      for (int u = 0; u < 16; ++u) {
        int ch = cg * 16 + u;
        ob[(size_t)ch * N_] = (y[u] - mean) * rstd * alpha[ch] + beta[ch];
      }
    }
  }
}

extern "C" void kernel_launch(void* const* d_in, const int* in_sizes, int n_in,
                              void* d_out, int out_size, void* d_ws, size_t ws_size,
                              hipStream_t stream) {
  const float* x     = (const float*)d_in[0];
  const float* wqkv  = (const float*)d_in[1];
  const float* wout  = (const float*)d_in[2];
  const float* bout  = (const float*)d_in[3];
  const float* alpha = (const float*)d_in[4];
  const float* beta  = (const float*)d_in[5];
  float* outp = (float*)d_out;

  // workspace layout: G | Pf | Sf | records
  float* G  = (float*)d_ws;                          // [B][128][128]
  float* Pf = G + (size_t)B_ * 16384;                // [B][4096]
  float* Sf = Pf + (size_t)B_ * 4096;                // [B][128]
  float* Ws = Sf + (size_t)B_ * 128;                 // [B*bpb][4224]

  size_t need128 = ((size_t)B_ * 16384 + B_ * 4096 + B_ * 128 +
                    (size_t)B_ * 128 * REC_) * sizeof(float);
  int bpb = (ws_size >= need128) ? 128 : 32;

  lin_attn_ctx<<<dim3(B_ * bpb), dim3(256), 0, stream>>>(x, wqkv, Ws);
  lin_attn_reduce<<<dim3(132), dim3(256), 0, stream>>>(Ws, bpb, Pf, Sf);
  lin_attn_gmat<<<dim3(B_ * 64), dim3(256), 0, stream>>>(Pf, Sf, wout, G);
  lin_attn_out<<<dim3(B_ * 128), dim3(256), 0, stream>>>(x, wqkv, G, bout,
                                                         alpha, beta, outp);
}